// Round 1
// 179.120 us; speedup vs baseline: 1.0727x; 1.0727x over previous
//
#include <hip/hip_runtime.h>
#include <stdint.h>
#include <stddef.h>

#define N_NODES 100000
#define N_EDGES 1600000
#define F_IN 128
#define EMB 128
#define HEADS 4
#define D_HEAD 32
#define HIDDEN 256
#define BATCH 2048
#define CANDS 16
#define NSLOTS 32768  /* BATCH*CANDS slots, one per index (dups resolved by canonical check) */
#define WXBLOCKS 391  /* ceil(N_NODES/256); 4 chunks of 64 rows per block */
#define WTROWS 144    /* 128 W cols + 8 att-projection rows + 8 zero pad */
#define STR 136       /* padded row stride (shorts) */

typedef __attribute__((ext_vector_type(8))) short v8s;
typedef __attribute__((ext_vector_type(4))) float v4f;

__device__ __forceinline__ unsigned short f2bs(float f) {
  unsigned int u = __builtin_bit_cast(unsigned int, f);
  u = (u + 0x7fffu + ((u >> 16) & 1u)) >> 16;
  return (unsigned short)u;
}
__device__ __forceinline__ float bs2f(unsigned int s) {
  unsigned int u = (s & 0xffffu) << 16;
  return __builtin_bit_cast(float, u);
}

// ------- prep: padded Wt^T (+att-projection rows) + slot-map dedup (no memset) -
// nidx[v] = some slot i with idx[i]==v (last writer wins; consistent for all
// later readers). Poison-proof: consumers validate idx[nidx[dst]]==dst, which
// garbage can never satisfy for a non-needed dst.
__global__ __launch_bounds__(256) void k_prep(const float* __restrict__ W,
                                              const float* __restrict__ att_src,
                                              const float* __restrict__ att_dst,
                                              unsigned short* __restrict__ Wtp,
                                              const int* __restrict__ idx,
                                              int* __restrict__ nidx,
                                              int* __restrict__ cnt) {
  int i = blockIdx.x * 256 + threadIdx.x;
  if (i < 128 * STR) {
    int r = i / STR, c = i - r * STR;
    Wtp[i] = (c < 128) ? f2bs(W[c * 128 + r]) : (unsigned short)0;
  } else if (i < WTROWS * STR) {
    int ii = i - 128 * STR;
    int r = ii / STR, c = ii - r * STR;  // r: 0..15
    unsigned short v = 0;
    if (c < 128 && r < 8) {
      const float* att = (r < 4) ? att_src : att_dst;
      int hh = r & 3;
      float s = 0.f;
#pragma unroll
      for (int d = 0; d < 32; ++d) s += W[c * 128 + hh * 32 + d] * att[hh * 32 + d];
      v = f2bs(s);
    }
    Wtp[i] = v;
  }
  if (i < NSLOTS) {
    cnt[i] = 0;           // only zero-init the scatter needs (128 KB, in-kernel)
    nidx[idx[i]] = i;     // plain store; any winner is canonical
  }
}

// ------- fused: msg GEMM (blocks 0..255) + edge scatter (blocks 256..6505) ----
// msg GEMM depends on nothing GAT-side; hide it under the latency-bound scan.
__global__ __launch_bounds__(256) void k_scatmsg(const int* __restrict__ ei,
                                                 const int* __restrict__ idx,
                                                 const int* __restrict__ nidx,
                                                 int* __restrict__ cnt,
                                                 int* __restrict__ srclist,
                                                 const float* __restrict__ message,
                                                 const float* __restrict__ fc_w,
                                                 const float* __restrict__ fc_b,
                                                 float* __restrict__ msg) {
  __shared__ float Sm[8][256];   // 8 KB message tile (msg path only)
  __shared__ float red[8 * 128]; // 4 KB reduction
  int tid = threadIdx.x;
  if (blockIdx.x < 256) {
    int b0 = blockIdx.x * 8;
    for (int i = tid; i < 8 * 256; i += 256)
      Sm[i >> 8][i & 255] = message[(size_t)b0 * 256 + i];
    __syncthreads();
    int e = tid & 127, half = tid >> 7;
    float acc[8];
#pragma unroll
    for (int r = 0; r < 8; ++r) acc[r] = 0.f;
    const float* wrow = fc_w + (size_t)e * 256 + half * 128;
    for (int k = 0; k < 128; k += 4) {
      float4 w4 = *(const float4*)(wrow + k);
#pragma unroll
      for (int r = 0; r < 8; ++r) {
        float4 m4 = *(const float4*)(&Sm[r][half * 128 + k]);
        acc[r] += m4.x * w4.x + m4.y * w4.y + m4.z * w4.z + m4.w * w4.w;
      }
    }
    __syncthreads();
    if (half == 0) {
#pragma unroll
      for (int r = 0; r < 8; ++r) red[r * 128 + e] = acc[r];
    }
    __syncthreads();
    if (half == 1) {
#pragma unroll
      for (int r = 0; r < 8; ++r) red[r * 128 + e] += acc[r];
    }
    __syncthreads();
    for (int i = tid; i < 1024; i += 256)
      msg[(size_t)b0 * 128 + i] = red[i] + fc_b[i & 127];
  } else {
    int e = (blockIdx.x - 256) * 256 + tid;
    if (e >= N_EDGES) return;
    int dst = ei[N_EDGES + e];
    unsigned int ni = (unsigned int)nidx[dst];
    if (ni >= NSLOTS) return;      // reject poison / non-needed
    if (idx[ni] != dst) return;    // validate slot (poison-proof dedup)
    int pos = atomicAdd(&cnt[ni], 1);
    if (pos < 64) srclist[ni * 64 + pos] = ei[e];
  }
}

// ---------------- Wx = x @ W (MFMA), Wt staged in LDS once per 256 rows --------
__global__ __launch_bounds__(256) void k_wx(const float* __restrict__ x,
                                            const unsigned short* __restrict__ Wtp,
                                            unsigned short* __restrict__ Wx,
                                            float* __restrict__ a_s,
                                            float* __restrict__ a_d) {
  __shared__ unsigned short wt[WTROWS * STR];  // 39168 B
  __shared__ unsigned short xs[64 * STR];      // 17408 B
  int tid = threadIdx.x;

  {
    const uint4* s = (const uint4*)Wtp;
    uint4* d = (uint4*)wt;
#pragma unroll
    for (int it = 0; it < 10; ++it) {
      int i = it * 256 + tid;
      if (i < WTROWS * STR / 8) d[i] = s[i];
    }
  }

  int w = tid >> 6, lane = tid & 63;
  int m = lane & 15, quad = lane >> 4;

  for (int chunk = 0; chunk < 4; ++chunk) {
    int rbase = blockIdx.x * 256 + chunk * 64;

    float4 f[8];
#pragma unroll
    for (int it = 0; it < 4; ++it) {
      int cid = it * 256 + tid;
      int row = cid >> 4, c = cid & 15;
      int gr = rbase + row;
      if (gr >= N_NODES) gr = N_NODES - 1;
      const float4* gp = (const float4*)(x + (size_t)gr * 128 + c * 8);
      f[2 * it] = gp[0];
      f[2 * it + 1] = gp[1];
    }
#pragma unroll
    for (int it = 0; it < 4; ++it) {
      int cid = it * 256 + tid;
      int row = cid >> 4, c = cid & 15;
      float4 f0 = f[2 * it], f1 = f[2 * it + 1];
      v8s a;
      a[0] = (short)f2bs(f0.x); a[1] = (short)f2bs(f0.y);
      a[2] = (short)f2bs(f0.z); a[3] = (short)f2bs(f0.w);
      a[4] = (short)f2bs(f1.x); a[5] = (short)f2bs(f1.y);
      a[6] = (short)f2bs(f1.z); a[7] = (short)f2bs(f1.w);
      *(v8s*)(&xs[row * STR + c * 8]) = a;
    }
    __syncthreads();

    v8s afrag[4];
#pragma unroll
    for (int t = 0; t < 4; ++t)
      afrag[t] = *(const v8s*)(&xs[(w * 16 + m) * STR + t * 32 + quad * 8]);

    v4f acc[9];
#pragma unroll
    for (int nt = 0; nt < 9; ++nt) {
      v4f a0 = {0.f, 0.f, 0.f, 0.f};
      const unsigned short* brow = wt + (size_t)(nt * 16 + m) * STR;
#pragma unroll
      for (int t = 0; t < 4; ++t) {
        v8s b = *(const v8s*)(brow + t * 32 + quad * 8);
        a0 = __builtin_amdgcn_mfma_f32_16x16x32_bf16(afrag[t], b, a0, 0, 0, 0);
      }
      acc[nt] = a0;
    }

#pragma unroll
    for (int r = 0; r < 4; ++r) {
      int orow = rbase + w * 16 + quad * 4 + r;
      if (orow < N_NODES) {
        if (m < 4) a_s[(size_t)orow * 4 + m] = acc[8][r];
        else if (m < 8) a_d[(size_t)orow * 4 + m - 4] = acc[8][r];
      }
    }

    __syncthreads();
#pragma unroll
    for (int nt = 0; nt < 8; ++nt)
#pragma unroll
      for (int r = 0; r < 4; ++r)
        xs[(w * 16 + quad * 4 + r) * STR + nt * 16 + m] = f2bs(acc[nt][r]);
    asm volatile("s_waitcnt lgkmcnt(0)" ::: "memory");
#pragma unroll
    for (int j = 0; j < 4; ++j) {
      int fr = 4 * j + (lane >> 4);
      int fc = (lane & 15) * 8;
      int grow = rbase + w * 16 + fr;
      v8s v = *(const v8s*)(&xs[(w * 16 + fr) * STR + fc]);
      if (grow < N_NODES) *(v8s*)(&Wx[(size_t)grow * 128 + fc]) = v;
    }
    __syncthreads();
  }
}

// ---------------- per-dst aggregation: 4 dsts/wave, quarter-wave per dst -------
__global__ __launch_bounds__(256) void k_agg(const float* __restrict__ a_s,
                                             const float* __restrict__ a_d,
                                             const unsigned short* __restrict__ Wx,
                                             const int* __restrict__ idx,
                                             const int* __restrict__ nidx,
                                             const int* __restrict__ cnt,
                                             const int* __restrict__ srclist,
                                             const int* __restrict__ ei,
                                             const float* __restrict__ bias,
                                             unsigned short* __restrict__ hout) {
  __shared__ int sS[16][64];
  __shared__ float sW[16][64 * 4];
  int w = threadIdx.x >> 6, lane = threadIdx.x & 63;
  int q = lane >> 4, li = lane & 15;
  int wq = w * 4 + q;
  int wid = (blockIdx.x * 4 + w) * 4 + q;  // 0..NSLOTS-1
  int dst = idx[wid];
  bool act = (nidx[dst] == wid);  // canonical slot only (dups + garbage skip)
  int degRaw = 0, deg = 0;
  float4 ad4 = {0.f, 0.f, 0.f, 0.f};
  float4 dsum = {0.f, 0.f, 0.f, 0.f};
  if (act) {
    degRaw = cnt[wid];
    deg = degRaw < 64 ? degRaw : 64;
    ad4 = *(const float4*)(a_d + (size_t)dst * 4);
    for (int t = li; t < deg; t += 16) {
      int sv = srclist[wid * 64 + t];
      float4 as = *(const float4*)(a_s + (size_t)sv * 4);
      float e0 = as.x + ad4.x; e0 = e0 > 0.f ? e0 : 0.2f * e0;
      float e1 = as.y + ad4.y; e1 = e1 > 0.f ? e1 : 0.2f * e1;
      float e2 = as.z + ad4.z; e2 = e2 > 0.f ? e2 : 0.2f * e2;
      float e3 = as.w + ad4.w; e3 = e3 > 0.f ? e3 : 0.2f * e3;
      float4 w4;
      w4.x = __expf(e0); w4.y = __expf(e1);
      w4.z = __expf(e2); w4.w = __expf(e3);
      sS[wq][t] = sv;
      *(float4*)(&sW[wq][t * 4]) = w4;
      dsum.x += w4.x; dsum.y += w4.y; dsum.z += w4.z; dsum.w += w4.w;
    }
  }
  __syncthreads();
  if (!act) return;

#pragma unroll
  for (int o = 8; o >= 1; o >>= 1) {
    dsum.x += __shfl_xor(dsum.x, o);
    dsum.y += __shfl_xor(dsum.y, o);
    dsum.z += __shfl_xor(dsum.z, o);
    dsum.w += __shfl_xor(dsum.w, o);
  }

  int hh = li >> 2;
  float4 as4 = *(const float4*)(a_s + (size_t)dst * 4);
  float s0 = as4.x + ad4.x; s0 = s0 > 0.f ? s0 : 0.2f * s0;
  float s1 = as4.y + ad4.y; s1 = s1 > 0.f ? s1 : 0.2f * s1;
  float s2 = as4.z + ad4.z; s2 = s2 > 0.f ? s2 : 0.2f * s2;
  float s3 = as4.w + ad4.w; s3 = s3 > 0.f ? s3 : 0.2f * s3;
  float w0 = __expf(s0), w1 = __expf(s1), w2 = __expf(s2), w3 = __expf(s3);
  float wSelf = hh < 2 ? (hh == 0 ? w0 : w1) : (hh == 2 ? w2 : w3);
  float denE = hh < 2 ? (hh == 0 ? dsum.x : dsum.y) : (hh == 2 ? dsum.z : dsum.w);
  float den = denE + wSelf;

  float acc[8];
  {
    uint4 u = *(const uint4*)(Wx + (size_t)dst * 128 + li * 8);
    acc[0] = wSelf * bs2f(u.x); acc[1] = wSelf * bs2f(u.x >> 16);
    acc[2] = wSelf * bs2f(u.y); acc[3] = wSelf * bs2f(u.y >> 16);
    acc[4] = wSelf * bs2f(u.z); acc[5] = wSelf * bs2f(u.z >> 16);
    acc[6] = wSelf * bs2f(u.w); acc[7] = wSelf * bs2f(u.w >> 16);
  }

  if (degRaw > 64) {
    // correctness-only fallback (P ~ 1e-20): serial full-edge rescan
    float adH = hh < 2 ? (hh == 0 ? ad4.x : ad4.y) : (hh == 2 ? ad4.z : ad4.w);
    den = wSelf;
    for (int e = 0; e < N_EDGES; ++e) {
      if (ei[N_EDGES + e] == dst) {
        int sv = ei[e];
        float ash = a_s[(size_t)sv * 4 + hh];
        float ee = ash + adH; ee = ee > 0.f ? ee : 0.2f * ee;
        float wA = __expf(ee);
        den += wA;
        uint4 u = *(const uint4*)(Wx + (size_t)sv * 128 + li * 8);
        acc[0] += wA * bs2f(u.x); acc[1] += wA * bs2f(u.x >> 16);
        acc[2] += wA * bs2f(u.y); acc[3] += wA * bs2f(u.y >> 16);
        acc[4] += wA * bs2f(u.z); acc[5] += wA * bs2f(u.z >> 16);
        acc[6] += wA * bs2f(u.w); acc[7] += wA * bs2f(u.w >> 16);
      }
    }
  } else {
#pragma unroll 4
    for (int j = 0; j < deg; ++j) {
      int s = sS[wq][j];
      float wA = sW[wq][j * 4 + hh];
      uint4 u = *(const uint4*)(Wx + (size_t)s * 128 + li * 8);
      acc[0] += wA * bs2f(u.x); acc[1] += wA * bs2f(u.x >> 16);
      acc[2] += wA * bs2f(u.y); acc[3] += wA * bs2f(u.y >> 16);
      acc[4] += wA * bs2f(u.z); acc[5] += wA * bs2f(u.z >> 16);
      acc[6] += wA * bs2f(u.w); acc[7] += wA * bs2f(u.w >> 16);
    }
  }

  float inv = 1.0f / den;
  float4 b0 = *(const float4*)(bias + li * 8);
  float4 b1 = *(const float4*)(bias + li * 8 + 4);
  uint4 o;
  o.x = (unsigned int)f2bs(acc[0] * inv + b0.x)
      | ((unsigned int)f2bs(acc[1] * inv + b0.y) << 16);
  o.y = (unsigned int)f2bs(acc[2] * inv + b0.z)
      | ((unsigned int)f2bs(acc[3] * inv + b0.w) << 16);
  o.z = (unsigned int)f2bs(acc[4] * inv + b1.x)
      | ((unsigned int)f2bs(acc[5] * inv + b1.y) << 16);
  o.w = (unsigned int)f2bs(acc[6] * inv + b1.z)
      | ((unsigned int)f2bs(acc[7] * inv + b1.w) << 16);
  *(uint4*)(hout + (size_t)dst * 128 + li * 8) = o;
}

// ------- scoring only: gather h + dot vs precomputed msg + log_softmax --------
__global__ __launch_bounds__(256) void k_score(const float* __restrict__ msg,
                                               const unsigned short* __restrict__ h,
                                               const int* __restrict__ indices,
                                               float* __restrict__ out) {
  __shared__ float Sm[8 * 128];  // 4 KB staged msg rows
  __shared__ float sp[128];
  int tid = threadIdx.x;
  int b0 = blockIdx.x * 8;
  for (int i = tid; i < 1024; i += 256) Sm[i] = msg[(size_t)b0 * 128 + i];
  __syncthreads();

  int r = (tid & 127) >> 4, c = tid & 15, half = tid >> 7;
  int id = indices[(b0 + r) * 16 + c];
  const unsigned short* hr = h + (size_t)id * 128 + half * 64;
  const float* mr = Sm + r * 128 + half * 64;
  float dot = 0.f;
#pragma unroll
  for (int k = 0; k < 64; k += 8) {
    uint4 qv = *(const uint4*)(hr + k);
    float4 m0 = *(const float4*)(mr + k);
    float4 m1 = *(const float4*)(mr + k + 4);
    dot += bs2f(qv.x) * m0.x + bs2f(qv.x >> 16) * m0.y
         + bs2f(qv.y) * m0.z + bs2f(qv.y >> 16) * m0.w
         + bs2f(qv.z) * m1.x + bs2f(qv.z >> 16) * m1.y
         + bs2f(qv.w) * m1.z + bs2f(qv.w >> 16) * m1.w;
  }
  if (half == 1) sp[tid - 128] = dot;
  __syncthreads();
  if (half == 0) {
    dot += sp[tid];
    float mx = dot;
#pragma unroll
    for (int o = 1; o < 16; o <<= 1) mx = fmaxf(mx, __shfl_xor(mx, o));
    float ex = __expf(dot - mx);
    float sum = ex;
#pragma unroll
    for (int o = 1; o < 16; o <<= 1) sum += __shfl_xor(sum, o);
    float lse = mx + __logf(sum);
    out[(b0 + r) * 16 + c] = dot - lse;
  }
}

extern "C" void kernel_launch(void* const* d_in, const int* in_sizes, int n_in,
                              void* d_out, int out_size, void* d_ws, size_t ws_size,
                              hipStream_t stream) {
  (void)in_sizes; (void)n_in; (void)out_size; (void)ws_size;
  const float* message = (const float*)d_in[0];
  const float* x       = (const float*)d_in[1];
  const int*   ei      = (const int*)d_in[2];
  const int*   indices = (const int*)d_in[3];
  const float* W       = (const float*)d_in[4];
  const float* att_src = (const float*)d_in[5];
  const float* att_dst = (const float*)d_in[6];
  const float* bias    = (const float*)d_in[7];
  const float* fc_w    = (const float*)d_in[8];
  const float* fc_b    = (const float*)d_in[9];
  float* out = (float*)d_out;

  char* p = (char*)d_ws;
  auto alloc = [&](size_t bytes) -> char* {
    char* r = p;
    p += (bytes + 255) & ~(size_t)255;
    return r;
  };
  unsigned short* Wx = (unsigned short*)alloc((size_t)N_NODES * 128 * 2);
  unsigned short* h  = (unsigned short*)alloc((size_t)N_NODES * 128 * 2);
  float* a_s = (float*)alloc((size_t)N_NODES * 4 * 4);
  float* a_d = (float*)alloc((size_t)N_NODES * 4 * 4);
  unsigned short* Wtp = (unsigned short*)alloc((size_t)WTROWS * STR * 2);
  int* nidx      = (int*)alloc((size_t)N_NODES * 4);
  int* cnt       = (int*)alloc((size_t)NSLOTS * 4);
  int* srclist   = (int*)alloc((size_t)NSLOTS * 64 * 4);
  float* msg     = (float*)alloc((size_t)BATCH * 128 * 4);

  // no memset: cnt zeroed in k_prep; nidx validated at use (poison-proof)
  k_prep<<<128, 256, 0, stream>>>(W, att_src, att_dst, Wtp, indices, nidx, cnt);
  k_scatmsg<<<256 + N_EDGES / 256, 256, 0, stream>>>(ei, indices, nidx, cnt, srclist,
                                                     message, fc_w, fc_b, msg);
  k_wx<<<WXBLOCKS, 256, 0, stream>>>(x, Wtp, Wx, a_s, a_d);
  k_agg<<<NSLOTS / 16, 256, 0, stream>>>(a_s, a_d, Wx, indices, nidx, cnt, srclist, ei, bias, h);
  k_score<<<BATCH / 8, 256, 0, stream>>>(msg, h, indices, out);
}